// Round 6
// baseline (1102.731 us; speedup 1.0000x reference)
//
#include <hip/hip_runtime.h>
#include <hip/hip_bf16.h>

#define NC_  512
#define VOL_ 98

typedef __attribute__((ext_vector_type(8))) short bf16x8;
typedef __attribute__((ext_vector_type(4))) float f32x4;
typedef __attribute__((ext_vector_type(16))) float f32x16;
typedef unsigned int u32;
typedef unsigned short u16;

#define MFMA16(a,b,c) __builtin_amdgcn_mfma_f32_16x16x32_bf16((a),(b),(c),0,0,0)
#define MFMA32(a,b,c) __builtin_amdgcn_mfma_f32_32x32x16_bf16((a),(b),(c),0,0,0)

#define SWZ(r)  ((unsigned)(((r) & 7) << 4))
#define SWZV(d) ((unsigned)(((((d) & 7)) ^ (((d) & 8) >> 1)) << 4))

__device__ __forceinline__ u16 f2bf(float f) {
    u32 u = __float_as_uint(f);
    u32 r = (u + 0x7fffu + ((u >> 16) & 1u)) >> 16;
    return (u16)r;
}
__device__ __forceinline__ u32 cvt_pk(float lo, float hi) {
    u32 r;
    asm("v_cvt_pk_bf16_f32 %0, %1, %2" : "=v"(r) : "v"(lo), "v"(hi));
    return r;
}

// ---------------------------------------------------------------------------
// Kernel 0: convert weights to bf16 (Wq pre-scaled by hd^-0.5)
// ---------------------------------------------------------------------------
__global__ void k_conv(const float* __restrict__ wqkv, const float* __restrict__ wproj,
                       u16* __restrict__ o)
{
    int i = blockIdx.x * 256 + threadIdx.x;
    if (i < 196608) {
        float v = wqkv[i];
        if (i < 65536) v *= 0.17677669529663687f;   // fold q-scale into Wq
        o[i] = f2bf(v);
    } else if (i < 262144) {
        o[i] = f2bf(wproj[i - 196608]);
    }
}

// ---------------------------------------------------------------------------
// Kernel 1 (fused): LN + shift/reorder + QKV(32x32 MFMA, reg-B) + S^T attn
// -> ao (global, block-private, L2-hot) + tail output projection -> y
// one block per cuboid, 512 threads = 8 waves, 2 blocks/CU
// LDS: rn 50176 + Qs 7168 + Ks 7168 + Vt 8192 + rowbase 448 + labs 128 = 73280
// ---------------------------------------------------------------------------
__global__ __launch_bounds__(512, 4)
void k_attn(const float* __restrict__ x, const float* __restrict__ gamma,
            const float* __restrict__ beta, const u16* __restrict__ wbf,
            u16* __restrict__ ao, const u16* __restrict__ wpbf,
            const float* __restrict__ bp, float* __restrict__ y)
{
    __shared__ __align__(16) u16 rn[VOL_ * 256];   // swz [98][256]
    __shared__ __align__(16) u16 Qs[112 * 32];     // swz [112][32]
    __shared__ __align__(16) u16 Ks[112 * 32];     // swz [112][32]
    __shared__ __align__(16) u16 Vt[32 * 128];     // swz [d=32][k=128]
    __shared__ u32 rowbase[112];
    __shared__ unsigned char labs[128];

    const int rawb = blockIdx.x;
    const int bid = ((rawb & 7) << 8) | (rawb >> 3);   // XCD swizzle (2048%8==0, bijective)
    const int b  = bid >> 9, n = bid & 511;
    const int ti = n >> 6, hi = (n >> 3) & 7, wi = n & 7;
    const int tid = threadIdx.x;
    const int lane = tid & 63, wv = tid >> 6;
    const int c15 = lane & 15, g  = lane >> 4;
    const int c31 = lane & 31, g2 = lane >> 5;

    // ---- rowbase (x/y flat offsets incl. roll) + mask labels ----
    if (tid < 128) {
        int i = tid;
        int vt = (i >= 49) ? 1 : 0;
        int r  = i - vt * 49;
        int vh = r / 7, vw = r - vh * 7;
        int t = ti * 2 + vt, h = hi * 7 + vh, w = wi * 7 + vw;
        if (i < 112) {
            int ts = (t + 1) & 15;
            int hs = h + 3; if (hs >= 56) hs -= 56;
            int ws2 = w + 3; if (ws2 >= 56) ws2 -= 56;
            rowbase[i] = (i < VOL_) ? (u32)((((b * 16 + ts) * 56 + hs) * 56 + ws2) * 256) : 0u;
        }
        if (i < VOL_) {
            int tr = (t < 14) ? 0 : ((t < 15) ? 1 : 2);
            int hr = (h < 49) ? 0 : ((h < 53) ? 1 : 2);
            int wr = (w < 49) ? 0 : ((w < 53) ? 1 : 2);
            labs[i] = (unsigned char)(tr * 9 + hr * 3 + wr);
        } else {
            labs[i] = (unsigned char)255;
        }
    }
    // zero Vt k in [112,128) once
    {
        int d = tid >> 4, k = 112 + (tid & 15);
        unsigned a = (unsigned)(d * 256 + k * 2) ^ SWZV(d);
        *(u16*)((char*)Vt + a) = 0;
    }
    __syncthreads();

    // ---- LayerNorm + roll gather -> swizzled bf16 tile ----
    const float4 gm = *(const float4*)(gamma + lane * 4);
    const float4 be = *(const float4*)(beta  + lane * 4);
    for (int i = wv; i < VOL_; i += 8) {
        const float* xp = x + (size_t)rowbase[i] + lane * 4;
        float4 xv = *(const float4*)xp;
        float s  = xv.x + xv.y + xv.z + xv.w;
        float s2 = xv.x * xv.x + xv.y * xv.y + xv.z * xv.z + xv.w * xv.w;
        #pragma unroll
        for (int o = 1; o < 64; o <<= 1) { s += __shfl_xor(s, o); s2 += __shfl_xor(s2, o); }
        float mu  = s  * (1.0f / 256.0f);
        float var = s2 * (1.0f / 256.0f) - mu * mu;
        float rs  = rsqrtf(var + 1e-5f);
        unsigned a = ((unsigned)(i * 512 + lane * 8)) ^ SWZ(i);
        uint2 pk2;
        pk2.x = cvt_pk((xv.x - mu) * rs * gm.x + be.x, (xv.y - mu) * rs * gm.y + be.y);
        pk2.y = cvt_pk((xv.z - mu) * rs * gm.z + be.z, (xv.w - mu) * rs * gm.w + be.w);
        *(uint2*)((char*)rn + a) = pk2;
    }

    // kcol labels per lane (u32 of 4 bytes), constant across heads/mt
    u32 lab4[7];
    #pragma unroll
    for (int c = 0; c < 7; ++c) lab4[c] = *(const u32*)&labs[c * 16 + g * 4];

    for (int hh = 0; hh < 8; ++hh) {
        __syncthreads();   // prev head attn done; rn/labs/Vt-pad ready (hh=0)

        // ---- QKV proj: 12 units of 32x32x16 (3 proj x 4 mtiles), reg-B ----
        for (int u = wv; u < 12; u += 8) {
            int proj = u >> 2, mt = u & 3;
            int arow = mt * 32 + c31; if (arow > 111) arow = 111;
            const u16* wb = wbf + (size_t)(proj * 256 + hh * 32 + c31) * 256 + g2 * 8;
            f32x16 acc = {0,0,0,0,0,0,0,0,0,0,0,0,0,0,0,0};
            #pragma unroll
            for (int half = 0; half < 2; ++half) {
                bf16x8 Bf[8];
                #pragma unroll
                for (int kk = 0; kk < 8; ++kk)
                    Bf[kk] = *(const bf16x8*)(wb + (half * 8 + kk) * 16);
                #pragma unroll
                for (int kk = 0; kk < 8; ++kk) {
                    unsigned a = (unsigned)(arow * 512 + (half * 8 + kk) * 32 + g2 * 16) ^ SWZ(arow);
                    bf16x8 A = *(const bf16x8*)((const char*)rn + a);
                    acc = MFMA32(A, Bf[kk], acc);
                }
            }
            #pragma unroll
            for (int r = 0; r < 16; ++r) {
                int row  = (r & 3) + 8 * (r >> 2) + 4 * g2;
                int grow = mt * 32 + row;
                if (grow < 112) {
                    if (proj == 2) {       // V -> Vt transposed, zero-fill rows >= 98
                        float v = (grow < VOL_) ? acc[r] : 0.f;
                        unsigned a = (unsigned)(c31 * 256 + grow * 2) ^ SWZV(c31);
                        *(u16*)((char*)Vt + a) = f2bf(v);
                    } else {
                        char* dst = (char*)((proj == 0) ? Qs : Ks);
                        unsigned a = (unsigned)(grow * 64 + c31 * 2) ^ SWZ(grow);
                        *(u16*)(dst + a) = f2bf(acc[r]);
                    }
                }
            }
        }
        __syncthreads();

        // ---- attention per m-tile, S^T layout: lane holds S[qrow=c15][kcols] ----
        for (int mt = wv; mt < 7; mt += 8) {
            int qrow = mt * 16 + c15;
            int labr = labs[qrow];
            u32 labr4 = (u32)labr * 0x01010101u;
            unsigned qa = (unsigned)(qrow * 64 + g * 16) ^ SWZ(qrow);
            bf16x8 qB = *(const bf16x8*)((const char*)Qs + qa);

            f32x4 s[7];
            #pragma unroll
            for (int c = 0; c < 7; ++c) {
                int krow = c * 16 + c15;
                unsigned ka = (unsigned)(krow * 64 + g * 16) ^ SWZ(krow);
                bf16x8 kA = *(const bf16x8*)((const char*)Ks + ka);
                f32x4 z = {0.f, 0.f, 0.f, 0.f};
                s[c] = MFMA16(kA, qB, z);
            }
            // pass 1: masked row max (partial in-lane, then across g)
            float mx = -1e30f;
            #pragma unroll
            for (int c = 0; c < 7; ++c) {
                u32 xo = lab4[c] ^ labr4;
                #pragma unroll
                for (int i = 0; i < 4; ++i) {
                    bool ok = ((xo >> (8 * i)) & 255u) == 0u;
                    mx = fmaxf(mx, ok ? s[c][i] : -1e30f);
                }
            }
            mx = fmaxf(mx, __shfl_xor(mx, 16));
            mx = fmaxf(mx, __shfl_xor(mx, 32));
            // pass 2: exp + row sum
            float lsum = 0.f;
            #pragma unroll
            for (int c = 0; c < 7; ++c) {
                u32 xo = lab4[c] ^ labr4;
                #pragma unroll
                for (int i = 0; i < 4; ++i) {
                    bool ok = ((xo >> (8 * i)) & 255u) == 0u;
                    float e = ok ? __expf(s[c][i] - mx) : 0.f;
                    s[c][i] = e;
                    lsum += e;
                }
            }
            lsum += __shfl_xor(lsum, 16);
            lsum += __shfl_xor(lsum, 32);
            float inv = 1.0f / lsum;
            // pass 3: pack normalized P^T to bf16 pairs
            u32 pk[8][2];
            #pragma unroll
            for (int c = 0; c < 7; ++c) {
                pk[c][0] = cvt_pk(s[c][0] * inv, s[c][1] * inv);
                pk[c][1] = cvt_pk(s[c][2] * inv, s[c][3] * inv);
            }
            pk[7][0] = 0u; pk[7][1] = 0u;

            // PV: A-frag built by register shuffle-transpose of P^T
            f32x4 O0 = {0.f, 0.f, 0.f, 0.f}, O1 = {0.f, 0.f, 0.f, 0.f};
            const int src0 = c15 + 32 * (g & 1);
            const bool csel = (g >> 1) != 0;
            #pragma unroll
            for (int f = 0; f < 4; ++f) {
                union { bf16x8 v; u32 w[4]; } pa;
                #pragma unroll
                for (int w = 0; w < 4; ++w) {
                    int src = src0 + 16 * (w >> 1);
                    u32 r0 = (u32)__shfl((int)pk[2 * f][w & 1], src);
                    u32 r1 = (u32)__shfl((int)pk[2 * f + 1][w & 1], src);
                    pa.w[w] = csel ? r1 : r0;
                }
                unsigned av0 = (unsigned)(c15 * 256 + f * 64 + g * 16) ^ SWZV(c15);
                unsigned av1 = (unsigned)((16 + c15) * 256 + f * 64 + g * 16) ^ SWZV(16 + c15);
                bf16x8 vB0 = *(const bf16x8*)((const char*)Vt + av0);
                bf16x8 vB1 = *(const bf16x8*)((const char*)Vt + av1);
                O0 = MFMA16(pa.v, vB0, O0);
                O1 = MFMA16(pa.v, vB1, O1);
            }
            #pragma unroll
            for (int i = 0; i < 4; ++i) {
                int grow = mt * 16 + g * 4 + i;
                if (grow < VOL_) {
                    size_t base = ((size_t)bid * VOL_ + grow) * 256 + hh * 32;
                    ao[base + c15]      = f2bf(O0[i]);
                    ao[base + 16 + c15] = f2bf(O1[i]);
                }
            }
        }
    }

    // ---- tail: output projection from ao (block-private, L2-hot) + scatter ----
    __threadfence();
    __syncthreads();
    for (int u = wv; u < 32; u += 8) {
        int nt = u >> 2, mt = u & 3;
        int arow = mt * 32 + c31; if (arow > 97) arow = 97;
        const u16* ap = ao + ((size_t)bid * VOL_ + arow) * 256 + g2 * 8;
        const u16* wb = wpbf + (size_t)(nt * 32 + c31) * 256 + g2 * 8;
        f32x16 acc = {0,0,0,0,0,0,0,0,0,0,0,0,0,0,0,0};
        #pragma unroll
        for (int half = 0; half < 2; ++half) {
            bf16x8 Bf[8];
            #pragma unroll
            for (int kk = 0; kk < 8; ++kk)
                Bf[kk] = *(const bf16x8*)(wb + (half * 8 + kk) * 16);
            #pragma unroll
            for (int kk = 0; kk < 8; ++kk) {
                bf16x8 A = *(const bf16x8*)(ap + (half * 8 + kk) * 16);
                acc = MFMA32(A, Bf[kk], acc);
            }
        }
        float bias = bp[nt * 32 + c31];
        #pragma unroll
        for (int r = 0; r < 16; ++r) {
            int row = (r & 3) + 8 * (r >> 2) + 4 * g2 + mt * 32;
            if (row < VOL_) {
                y[(size_t)rowbase[row] + nt * 32 + c31] = acc[r] + bias;
            }
        }
    }
}

extern "C" void kernel_launch(void* const* d_in, const int* in_sizes, int n_in,
                              void* d_out, int out_size, void* d_ws, size_t ws_size,
                              hipStream_t stream) {
    const float* x     = (const float*)d_in[0];
    const float* gamma = (const float*)d_in[1];
    const float* beta  = (const float*)d_in[2];
    const float* wqkv  = (const float*)d_in[3];
    const float* wproj = (const float*)d_in[4];
    const float* bproj = (const float*)d_in[5];
    float* y = (float*)d_out;

    u16* wbf  = (u16*)d_ws;            // 196608 (qkv) + 65536 (proj)
    u16* wpbf = wbf + 196608;
    u16* ao   = wbf + 262144;          // 2048*98*256 bf16 = 102.8 MB

    k_conv<<<dim3(1024), dim3(256), 0, stream>>>(wqkv, wproj, wbf);
    k_attn<<<dim3(4 * NC_), dim3(512), 0, stream>>>(x, gamma, beta, wbf, ao, wpbf, bproj, y);
}

// Round 7
// 613.065 us; speedup vs baseline: 1.7987x; 1.7987x over previous
//
#include <hip/hip_runtime.h>
#include <hip/hip_bf16.h>

#define NC_  512
#define VOL_ 98

typedef __attribute__((ext_vector_type(8))) short bf16x8;
typedef __attribute__((ext_vector_type(4))) float f32x4;
typedef __attribute__((ext_vector_type(16))) float f32x16;
typedef unsigned int u32;
typedef unsigned short u16;

#define MFMA16(a,b,c) __builtin_amdgcn_mfma_f32_16x16x32_bf16((a),(b),(c),0,0,0)
#define MFMA32(a,b,c) __builtin_amdgcn_mfma_f32_32x32x16_bf16((a),(b),(c),0,0,0)

#define SWZ(r)   ((unsigned)(((r) & 7) << 4))    // 64B-row tiles (Qs/Ks)
#define SWZ5(r)  ((unsigned)(((r) & 31) << 4))   // 512B-row tiles (rn/tile): full 32-slot spread
#define SWZV(d)  ((unsigned)(((d) & 15) << 4))   // 256B-row Vt

__device__ __forceinline__ u16 f2bf(float f) {
    u32 u = __float_as_uint(f);
    u32 r = (u + 0x7fffu + ((u >> 16) & 1u)) >> 16;
    return (u16)r;
}
__device__ __forceinline__ u32 cvt_pk(float lo, float hi) {
    u32 r;
    asm("v_cvt_pk_bf16_f32 %0, %1, %2" : "=v"(r) : "v"(lo), "v"(hi));
    return r;
}

// ---------------------------------------------------------------------------
// Kernel 0: convert weights to bf16 (Wq pre-scaled by hd^-0.5)
// ---------------------------------------------------------------------------
__global__ void k_conv(const float* __restrict__ wqkv, const float* __restrict__ wproj,
                       u16* __restrict__ o)
{
    int i = blockIdx.x * 256 + threadIdx.x;
    if (i < 196608) {
        float v = wqkv[i];
        if (i < 65536) v *= 0.17677669529663687f;   // fold q-scale into Wq
        o[i] = f2bf(v);
    } else if (i < 262144) {
        o[i] = f2bf(wproj[i - 196608]);
    }
}

// ---------------------------------------------------------------------------
// Kernel 1: LN + shift/reorder + QKV(32x32 MFMA, reg-B) + S^T attention -> ao
// one block per cuboid, 512 threads = 8 waves, 2 blocks/CU
// ---------------------------------------------------------------------------
__global__ __launch_bounds__(512, 4)
void k_attn(const float* __restrict__ x, const float* __restrict__ gamma,
            const float* __restrict__ beta, const u16* __restrict__ wbf,
            u16* __restrict__ ao)
{
    __shared__ __align__(16) u16 rn[VOL_ * 256];   // swz5 [98][256]
    __shared__ __align__(16) u16 Qs[112 * 32];     // swz [112][32]
    __shared__ __align__(16) u16 Ks[112 * 32];     // swz [112][32]
    __shared__ __align__(16) u16 Vt[32 * 128];     // swzV [d=32][k=128]
    __shared__ u32 rowbase[112];
    __shared__ unsigned char labs[128];

    const int rawb = blockIdx.x;
    const int bid = ((rawb & 7) << 8) | (rawb >> 3);   // XCD swizzle (2048%8==0, bijective)
    const int b  = bid >> 9, n = bid & 511;
    const int ti = n >> 6, hi = (n >> 3) & 7, wi = n & 7;
    const int tid = threadIdx.x;
    const int lane = tid & 63, wv = tid >> 6;
    const int c15 = lane & 15, g  = lane >> 4;
    const int c31 = lane & 31, g2 = lane >> 5;

    // ---- rowbase (x/y flat offsets incl. roll) + mask labels ----
    if (tid < 128) {
        int i = tid;
        int vt = (i >= 49) ? 1 : 0;
        int r  = i - vt * 49;
        int vh = r / 7, vw = r - vh * 7;
        int t = ti * 2 + vt, h = hi * 7 + vh, w = wi * 7 + vw;
        if (i < 112) {
            int ts = (t + 1) & 15;
            int hs = h + 3; if (hs >= 56) hs -= 56;
            int ws2 = w + 3; if (ws2 >= 56) ws2 -= 56;
            rowbase[i] = (i < VOL_) ? (u32)((((b * 16 + ts) * 56 + hs) * 56 + ws2) * 256) : 0u;
        }
        if (i < VOL_) {
            int tr = (t < 14) ? 0 : ((t < 15) ? 1 : 2);
            int hr = (h < 49) ? 0 : ((h < 53) ? 1 : 2);
            int wr = (w < 49) ? 0 : ((w < 53) ? 1 : 2);
            labs[i] = (unsigned char)(tr * 9 + hr * 3 + wr);
        } else {
            labs[i] = (unsigned char)255;
        }
    }
    // zero Vt k in [112,128) once (u32 writes)
    if (tid < 256) {
        int d = tid >> 3, kp = 112 + (tid & 7) * 2;
        unsigned a = (unsigned)(d * 256 + kp * 2) ^ SWZV(d);
        *(u32*)((char*)Vt + a) = 0u;
    }
    __syncthreads();

    // ---- LayerNorm + roll gather -> swizzled bf16 tile ----
    const float4 gm = *(const float4*)(gamma + lane * 4);
    const float4 be = *(const float4*)(beta  + lane * 4);
    for (int i = wv; i < VOL_; i += 8) {
        const float* xp = x + (size_t)rowbase[i] + lane * 4;
        float4 xv = *(const float4*)xp;
        float s  = xv.x + xv.y + xv.z + xv.w;
        float s2 = xv.x * xv.x + xv.y * xv.y + xv.z * xv.z + xv.w * xv.w;
        #pragma unroll
        for (int o = 1; o < 64; o <<= 1) { s += __shfl_xor(s, o); s2 += __shfl_xor(s2, o); }
        float mu  = s  * (1.0f / 256.0f);
        float var = s2 * (1.0f / 256.0f) - mu * mu;
        float rs  = rsqrtf(var + 1e-5f);
        unsigned a = ((unsigned)(i * 512 + lane * 8)) ^ SWZ5(i);
        uint2 pk2;
        pk2.x = cvt_pk((xv.x - mu) * rs * gm.x + be.x, (xv.y - mu) * rs * gm.y + be.y);
        pk2.y = cvt_pk((xv.z - mu) * rs * gm.z + be.z, (xv.w - mu) * rs * gm.w + be.w);
        *(uint2*)((char*)rn + a) = pk2;
    }

    // kcol labels per lane (u32 of 4 bytes), constant across heads/mt
    u32 lab4[7];
    #pragma unroll
    for (int c = 0; c < 7; ++c) lab4[c] = *(const u32*)&labs[c * 16 + g * 4];

    for (int hh = 0; hh < 8; ++hh) {
        __syncthreads();   // prev head attn done; rn/labs/Vt-pad ready (hh=0)

        // ---- QKV proj: 12 units of 32x32x16 (3 proj x 4 mtiles), reg-B ----
        for (int u = wv; u < 12; u += 8) {
            int proj = u >> 2, mt = u & 3;
            int arow = mt * 32 + c31; if (arow > 111) arow = 111;
            const u16* wb = wbf + (size_t)(proj * 256 + hh * 32 + c31) * 256 + g2 * 8;
            f32x16 acc = {0,0,0,0,0,0,0,0,0,0,0,0,0,0,0,0};
            #pragma unroll
            for (int half = 0; half < 2; ++half) {
                bf16x8 Bf[8];
                #pragma unroll
                for (int kk = 0; kk < 8; ++kk)
                    Bf[kk] = *(const bf16x8*)(wb + (half * 8 + kk) * 16);
                #pragma unroll
                for (int kk = 0; kk < 8; ++kk) {
                    unsigned a = (unsigned)(arow * 512 + (half * 8 + kk) * 32 + g2 * 16) ^ SWZ5(arow);
                    bf16x8 A = *(const bf16x8*)((const char*)rn + a);
                    acc = MFMA32(A, Bf[kk], acc);
                }
            }
            if (proj == 2) {           // V -> Vt transposed, packed u32 pairs, zero pad
                #pragma unroll
                for (int r = 0; r < 16; r += 2) {
                    int kpos = mt * 32 + (r & 3) + 8 * (r >> 2) + 4 * g2;
                    float v0 = (kpos < VOL_)     ? acc[r]     : 0.f;
                    float v1 = (kpos + 1 < VOL_) ? acc[r + 1] : 0.f;
                    unsigned a = (unsigned)(c31 * 256 + kpos * 2) ^ SWZV(c31);
                    *(u32*)((char*)Vt + a) = cvt_pk(v0, v1);
                }
            } else {
                char* dst = (char*)((proj == 0) ? Qs : Ks);
                #pragma unroll
                for (int r = 0; r < 16; ++r) {
                    int grow = mt * 32 + (r & 3) + 8 * (r >> 2) + 4 * g2;
                    if (grow < 112) {
                        unsigned a = (unsigned)(grow * 64 + c31 * 2) ^ SWZ(grow);
                        *(u16*)(dst + a) = f2bf(acc[r]);
                    }
                }
            }
        }
        __syncthreads();

        // ---- attention per m-tile, S^T layout: lane holds S[qrow=c15][kcols] ----
        for (int mt = wv; mt < 7; mt += 8) {
            int qrow = mt * 16 + c15;
            int labr = labs[qrow];
            u32 labr4 = (u32)labr * 0x01010101u;
            unsigned qa = (unsigned)(qrow * 64 + g * 16) ^ SWZ(qrow);
            bf16x8 qB = *(const bf16x8*)((const char*)Qs + qa);

            f32x4 s[7];
            #pragma unroll
            for (int c = 0; c < 7; ++c) {
                int krow = c * 16 + c15;
                unsigned ka = (unsigned)(krow * 64 + g * 16) ^ SWZ(krow);
                bf16x8 kA = *(const bf16x8*)((const char*)Ks + ka);
                f32x4 z = {0.f, 0.f, 0.f, 0.f};
                s[c] = MFMA16(kA, qB, z);
            }
            // pass 1: masked row max (in-lane, then across g)
            float mx = -1e30f;
            #pragma unroll
            for (int c = 0; c < 7; ++c) {
                u32 xo = lab4[c] ^ labr4;
                #pragma unroll
                for (int i = 0; i < 4; ++i) {
                    bool ok = ((xo >> (8 * i)) & 255u) == 0u;
                    mx = fmaxf(mx, ok ? s[c][i] : -1e30f);
                }
            }
            mx = fmaxf(mx, __shfl_xor(mx, 16));
            mx = fmaxf(mx, __shfl_xor(mx, 32));
            // pass 2: exp + row sum
            float lsum = 0.f;
            #pragma unroll
            for (int c = 0; c < 7; ++c) {
                u32 xo = lab4[c] ^ labr4;
                #pragma unroll
                for (int i = 0; i < 4; ++i) {
                    bool ok = ((xo >> (8 * i)) & 255u) == 0u;
                    float e = ok ? __expf(s[c][i] - mx) : 0.f;
                    s[c][i] = e;
                    lsum += e;
                }
            }
            lsum += __shfl_xor(lsum, 16);
            lsum += __shfl_xor(lsum, 32);
            float inv = 1.0f / lsum;
            // pass 3: pack normalized P^T to bf16 pairs
            u32 pk[8][2];
            #pragma unroll
            for (int c = 0; c < 7; ++c) {
                pk[c][0] = cvt_pk(s[c][0] * inv, s[c][1] * inv);
                pk[c][1] = cvt_pk(s[c][2] * inv, s[c][3] * inv);
            }
            pk[7][0] = 0u; pk[7][1] = 0u;

            // PV: A-frag built by register shuffle-transpose of P^T
            f32x4 O0 = {0.f, 0.f, 0.f, 0.f}, O1 = {0.f, 0.f, 0.f, 0.f};
            const int src0 = c15 + 32 * (g & 1);
            const bool csel = (g >> 1) != 0;
            #pragma unroll
            for (int f = 0; f < 4; ++f) {
                union { bf16x8 v; u32 w[4]; } pa;
                #pragma unroll
                for (int w = 0; w < 4; ++w) {
                    int src = src0 + 16 * (w >> 1);
                    u32 r0 = (u32)__shfl((int)pk[2 * f][w & 1], src);
                    u32 r1 = (u32)__shfl((int)pk[2 * f + 1][w & 1], src);
                    pa.w[w] = csel ? r1 : r0;
                }
                unsigned av0 = (unsigned)(c15 * 256 + f * 64 + g * 16) ^ SWZV(c15);
                unsigned av1 = (unsigned)((16 + c15) * 256 + f * 64 + g * 16) ^ SWZV(16 + c15);
                bf16x8 vB0 = *(const bf16x8*)((const char*)Vt + av0);
                bf16x8 vB1 = *(const bf16x8*)((const char*)Vt + av1);
                O0 = MFMA16(pa.v, vB0, O0);
                O1 = MFMA16(pa.v, vB1, O1);
            }
            #pragma unroll
            for (int i = 0; i < 4; ++i) {
                int grow = mt * 16 + g * 4 + i;
                if (grow < VOL_) {
                    size_t base = ((size_t)bid * VOL_ + grow) * 256 + hh * 32;
                    ao[base + c15]      = f2bf(O0[i]);
                    ao[base + 16 + c15] = f2bf(O1[i]);
                }
            }
        }
    }
}

// ---------------------------------------------------------------------------
// Kernel 2: output projection (32x32 MFMA, reg-B) + reverse reorder + roll
// 512 threads = 8 waves; 32 units (8 nt x 4 mt)
// ---------------------------------------------------------------------------
__global__ __launch_bounds__(512, 4)
void k_proj(const u16* __restrict__ ao, const u16* __restrict__ wpbf,
            const float* __restrict__ bp, float* __restrict__ y)
{
    __shared__ __align__(16) u16 tile[VOL_ * 256];   // swz5 [98][256]
    __shared__ u32 rowbase[112];
    const int rawb = blockIdx.x;
    const int bid = ((rawb & 7) << 8) | (rawb >> 3);   // same XCD swizzle as k_attn
    const int b  = bid >> 9, n = bid & 511;
    const int ti = n >> 6, hi = (n >> 3) & 7, wi = n & 7;
    const int tid = threadIdx.x;
    const int c31 = (tid & 63) & 31, g2 = (tid & 63) >> 5;
    const int wv = tid >> 6;

    if (tid < 112) {
        int i = tid;
        int vt = (i >= 49) ? 1 : 0;
        int r  = i - vt * 49;
        int vh = r / 7, vw = r - vh * 7;
        int t = ti * 2 + vt, h = hi * 7 + vh, w = wi * 7 + vw;
        int ts = (t + 1) & 15;
        int hs = h + 3; if (hs >= 56) hs -= 56;
        int ws2 = w + 3; if (ws2 >= 56) ws2 -= 56;
        rowbase[i] = (i < VOL_) ? (u32)((((b * 16 + ts) * 56 + hs) * 56 + ws2) * 256) : 0u;
    }
    const uint4* src = (const uint4*)(ao + (size_t)bid * (VOL_ * 256));
    for (int cidx = tid; cidx < (VOL_ * 256) / 8; cidx += 512) {
        uint4 v = src[cidx];
        int row = cidx >> 5, blk = cidx & 31;
        unsigned a = (unsigned)((row << 9) + (blk << 4)) ^ SWZ5(row);
        *(uint4*)((char*)tile + a) = v;
    }
    __syncthreads();

    for (int u = wv; u < 32; u += 8) {
        int nt = u >> 2, mt = u & 3;
        int arow = mt * 32 + c31; if (arow > 97) arow = 97;
        const u16* wb = wpbf + (size_t)(nt * 32 + c31) * 256 + g2 * 8;
        f32x16 acc = {0,0,0,0,0,0,0,0,0,0,0,0,0,0,0,0};
        #pragma unroll
        for (int half = 0; half < 2; ++half) {
            bf16x8 Bf[8];
            #pragma unroll
            for (int kk = 0; kk < 8; ++kk)
                Bf[kk] = *(const bf16x8*)(wb + (half * 8 + kk) * 16);
            #pragma unroll
            for (int kk = 0; kk < 8; ++kk) {
                unsigned a = (unsigned)(arow * 512 + (half * 8 + kk) * 32 + g2 * 16) ^ SWZ5(arow);
                bf16x8 A = *(const bf16x8*)((const char*)tile + a);
                acc = MFMA32(A, Bf[kk], acc);
            }
        }
        float bias = bp[nt * 32 + c31];
        #pragma unroll
        for (int r = 0; r < 16; ++r) {
            int row = (r & 3) + 8 * (r >> 2) + 4 * g2 + mt * 32;
            if (row < VOL_) {
                y[(size_t)rowbase[row] + nt * 32 + c31] = acc[r] + bias;
            }
        }
    }
}

extern "C" void kernel_launch(void* const* d_in, const int* in_sizes, int n_in,
                              void* d_out, int out_size, void* d_ws, size_t ws_size,
                              hipStream_t stream) {
    const float* x     = (const float*)d_in[0];
    const float* gamma = (const float*)d_in[1];
    const float* beta  = (const float*)d_in[2];
    const float* wqkv  = (const float*)d_in[3];
    const float* wproj = (const float*)d_in[4];
    const float* bproj = (const float*)d_in[5];
    float* y = (float*)d_out;

    u16* wbf  = (u16*)d_ws;            // 196608 (qkv) + 65536 (proj)
    u16* wpbf = wbf + 196608;
    u16* ao   = wbf + 262144;          // 2048*98*256 bf16 = 102.8 MB

    k_conv<<<dim3(1024), dim3(256), 0, stream>>>(wqkv, wproj, wbf);
    k_attn<<<dim3(4 * NC_), dim3(512), 0, stream>>>(x, gamma, beta, wbf, ao);
    k_proj<<<dim3(4 * NC_), dim3(512), 0, stream>>>(ao, wpbf, bproj, y);
}